// Round 20
// baseline (489.050 us; speedup 1.0000x reference)
//
#include <hip/hip_runtime.h>
#include <math.h>

// AttnBlock: GroupNorm -> QKV 1x1 conv -> spatial self-attention -> proj 1x1 conv + residual
// x (4, 512, 64, 64) fp32. B=4, C=512, N=HW=4096, 32 groups of 16 ch.
// Round 20: LDS-BW attack. Audit: attn iter moves ~640KB through the 256B/cyc
// LDS port = 2500cyc ~= measured 2570cyc -> LDS-BW-bound. PV re-mapped to
// (32-row half x 128-c quarter) waves: each V fragment feeds 2 row-subtiles
// (V redundancy 4x->2x, -128KB/iter). Softmax branchless (defer-max dropped:
// its per-wave __all decision breaks QK-row/PV-row scaling consistency).
// QK phase / staging / barriers / swizzles byte-identical to r17.

#define BATCH 4
#define CH    512
#define NPOS  4096
#define NGRP  32
#define GSIZE (16 * NPOS)
#define WSZ   262144   // 512*512
#define KVB   64
#define NT    64       // 4096 / KVB

typedef __attribute__((ext_vector_type(8))) short bf16x8;
typedef __attribute__((ext_vector_type(4))) float f32x4;

__device__ __forceinline__ ushort f2b(float x) {   // fp32 -> bf16 RNE
    uint u = __float_as_uint(x);
    u += 0x7fff + ((u >> 16) & 1);
    return (ushort)(u >> 16);
}

// async global->LDS, 16B per lane (lds base wave-uniform, HW adds lane*16)
__device__ __forceinline__ void gld16(void* lds, const void* g) {
    __builtin_amdgcn_global_load_lds(
        (const __attribute__((address_space(1))) void*)g,
        (__attribute__((address_space(3))) void*)lds, 16, 0, 0);
}

// ---------------------------------------------------------------------------
// K1: merged prep — blocks 0..127: GroupNorm stats (one per (b,g) segment);
// blocks 128..639: W fp32->bf16 conversion. Independent work, one launch.
// ---------------------------------------------------------------------------
__global__ __launch_bounds__(256) void prep_k(
    const float* __restrict__ x, float* __restrict__ stats,
    const float* __restrict__ Wq, const float* __restrict__ Wk,
    const float* __restrict__ Wv, const float* __restrict__ Wp,
    ushort* __restrict__ W4) {
    if (blockIdx.x >= 128) {
        int id = blockIdx.x - 128;           // 512 conversion blocks
        int sel = id >> 7, blk = id & 127;
        const float* src = sel == 0 ? Wq : (sel == 1 ? Wk : (sel == 2 ? Wv : Wp));
        const float4* s4 = (const float4*)(src + (size_t)blk * 2048);
        ushort4* d4 = (ushort4*)(W4 + (size_t)sel * WSZ + (size_t)blk * 2048);
        for (int i = threadIdx.x; i < 512; i += 256) {
            float4 v = s4[i];
            d4[i] = make_ushort4(f2b(v.x), f2b(v.y), f2b(v.z), f2b(v.w));
        }
        return;
    }
    int bg = blockIdx.x;
    const float4* xp = reinterpret_cast<const float4*>(x + (size_t)bg * GSIZE);
    float s1 = 0.f, s2 = 0.f;
    for (int i = threadIdx.x; i < GSIZE / 4; i += 256) {
        float4 v = xp[i];
        s1 += v.x + v.y + v.z + v.w;
        s2 += v.x * v.x + v.y * v.y + v.z * v.z + v.w * v.w;
    }
    for (int off = 32; off > 0; off >>= 1) {
        s1 += __shfl_down(s1, off);
        s2 += __shfl_down(s2, off);
    }
    __shared__ float r1[4], r2[4];
    int wid = threadIdx.x >> 6;
    if ((threadIdx.x & 63) == 0) { r1[wid] = s1; r2[wid] = s2; }
    __syncthreads();
    if (threadIdx.x == 0) {
        float t1 = r1[0] + r1[1] + r1[2] + r1[3];
        float t2 = r2[0] + r2[1] + r2[2] + r2[3];
        float mean = t1 / (float)GSIZE;
        float var  = t2 / (float)GSIZE - mean * mean;
        stats[bg]       = mean;
        stats[128 + bg] = rsqrtf(var + 1e-6f);
    }
}

// ---------------------------------------------------------------------------
// K2: GroupNorm apply + transpose: x[b][c][m] fp32 -> hnT[b][m][c] bf16.
// grid (64 mt, 8 ct, 4 b), 64x64 tiles via LDS.
// ---------------------------------------------------------------------------
__global__ __launch_bounds__(256) void hnT_k(
    const float* __restrict__ x, const float* __restrict__ gamma,
    const float* __restrict__ beta, const float* __restrict__ stats,
    ushort* __restrict__ hnT) {
    int bm = blockIdx.x * 64, c0 = blockIdx.y * 64, b = blockIdx.z;
    __shared__ ushort Ls[64][65];
    int t = threadIdx.x, tx = t & 15, ty = t >> 4;
    const float* xb = x + ((size_t)b * CH + c0) * NPOS + bm;
#pragma unroll
    for (int it = 0; it < 4; ++it) {
        int cc = ty + it * 16;
        int ch = c0 + cc;
        int bg = b * NGRP + (ch >> 4);
        float ga = stats[128 + bg] * gamma[ch];
        float be = beta[ch] - stats[bg] * ga;
        float4 v = *(const float4*)(xb + (size_t)cc * NPOS + tx * 4);
        Ls[cc][tx * 4 + 0] = f2b(v.x * ga + be);
        Ls[cc][tx * 4 + 1] = f2b(v.y * ga + be);
        Ls[cc][tx * 4 + 2] = f2b(v.z * ga + be);
        Ls[cc][tx * 4 + 3] = f2b(v.w * ga + be);
    }
    __syncthreads();
#pragma unroll
    for (int it = 0; it < 4; ++it) {
        int mm = ty + it * 16;
        ushort4 o;
        o.x = Ls[tx * 4 + 0][mm];
        o.y = Ls[tx * 4 + 1][mm];
        o.z = Ls[tx * 4 + 2][mm];
        o.w = Ls[tx * 4 + 3][mm];
        *(ushort4*)(hnT + ((size_t)(b * NPOS) + bm + mm) * CH + c0 + tx * 4) = o;
    }
}

// ---------------------------------------------------------------------------
// K3: QKV GEMM on MFMA, no LDS, depth-1 load pipeline.
// grid (64 mt, 8 ot, 4 b), 4 waves; wave tile 32m x 32o, all 3 outputs.
// Outputs: qT[b][m][o] (pre-scaled), kT[b][m][o], vB[b][o][m].
// ---------------------------------------------------------------------------
__global__ __launch_bounds__(256) void qkv3_k(
    const ushort* __restrict__ hnT, const ushort* __restrict__ W4,
    const float* __restrict__ bq, const float* __restrict__ bk,
    const float* __restrict__ bv,
    ushort* __restrict__ qT, ushort* __restrict__ kT, ushort* __restrict__ vB) {
    int bm = blockIdx.x * 64, bo = blockIdx.y * 64, b = blockIdx.z;
    int t = threadIdx.x, l = t & 63, w = t >> 6;
    int wr = w & 1, wc = w >> 1;
    int lr = l & 15, lg = l >> 4;

    const ushort* ha  = hnT + ((size_t)(b * NPOS) + bm + wr * 32 + lr) * CH + lg * 8;
    const ushort* wqp = W4 + (size_t)(bo + wc * 32 + lr) * CH + lg * 8;
    const ushort* wkp = wqp + WSZ;
    const ushort* wvp = wkp + WSZ;

    f32x4 aq[2][2], ak[2][2], av[2][2];
#pragma unroll
    for (int i = 0; i < 2; ++i)
#pragma unroll
        for (int j = 0; j < 2; ++j) {
            aq[i][j] = (f32x4){0.f, 0.f, 0.f, 0.f};
            ak[i][j] = (f32x4){0.f, 0.f, 0.f, 0.f};
            av[i][j] = (f32x4){0.f, 0.f, 0.f, 0.f};
        }
    // prologue loads (step 0)
    bf16x8 a0 = *(const bf16x8*)(ha);
    bf16x8 a1 = *(const bf16x8*)(ha + 16 * CH);
    bf16x8 q0 = *(const bf16x8*)(wqp);
    bf16x8 q1 = *(const bf16x8*)(wqp + 16 * CH);
    bf16x8 k0 = *(const bf16x8*)(wkp);
    bf16x8 k1 = *(const bf16x8*)(wkp + 16 * CH);
    bf16x8 v0 = *(const bf16x8*)(wvp);
    bf16x8 v1 = *(const bf16x8*)(wvp + 16 * CH);
#pragma unroll
    for (int s = 0; s < 16; ++s) {
        bf16x8 na0, na1, nq0, nq1, nk0, nk1, nv0, nv1;
        if (s < 15) {                          // prefetch step s+1
            int c1 = (s + 1) * 32;
            na0 = *(const bf16x8*)(ha + c1);
            na1 = *(const bf16x8*)(ha + 16 * CH + c1);
            nq0 = *(const bf16x8*)(wqp + c1);
            nq1 = *(const bf16x8*)(wqp + 16 * CH + c1);
            nk0 = *(const bf16x8*)(wkp + c1);
            nk1 = *(const bf16x8*)(wkp + 16 * CH + c1);
            nv0 = *(const bf16x8*)(wvp + c1);
            nv1 = *(const bf16x8*)(wvp + 16 * CH + c1);
        }
        aq[0][0] = __builtin_amdgcn_mfma_f32_16x16x32_bf16(a0, q0, aq[0][0], 0, 0, 0);
        aq[0][1] = __builtin_amdgcn_mfma_f32_16x16x32_bf16(a0, q1, aq[0][1], 0, 0, 0);
        aq[1][0] = __builtin_amdgcn_mfma_f32_16x16x32_bf16(a1, q0, aq[1][0], 0, 0, 0);
        aq[1][1] = __builtin_amdgcn_mfma_f32_16x16x32_bf16(a1, q1, aq[1][1], 0, 0, 0);
        ak[0][0] = __builtin_amdgcn_mfma_f32_16x16x32_bf16(a0, k0, ak[0][0], 0, 0, 0);
        ak[0][1] = __builtin_amdgcn_mfma_f32_16x16x32_bf16(a0, k1, ak[0][1], 0, 0, 0);
        ak[1][0] = __builtin_amdgcn_mfma_f32_16x16x32_bf16(a1, k0, ak[1][0], 0, 0, 0);
        ak[1][1] = __builtin_amdgcn_mfma_f32_16x16x32_bf16(a1, k1, ak[1][1], 0, 0, 0);
        av[0][0] = __builtin_amdgcn_mfma_f32_16x16x32_bf16(v0, a0, av[0][0], 0, 0, 0);
        av[0][1] = __builtin_amdgcn_mfma_f32_16x16x32_bf16(v0, a1, av[0][1], 0, 0, 0);
        av[1][0] = __builtin_amdgcn_mfma_f32_16x16x32_bf16(v1, a0, av[1][0], 0, 0, 0);
        av[1][1] = __builtin_amdgcn_mfma_f32_16x16x32_bf16(v1, a1, av[1][1], 0, 0, 0);
        if (s < 15) {
            a0 = na0; a1 = na1; q0 = nq0; q1 = nq1;
            k0 = nk0; k1 = nk1; v0 = nv0; v1 = nv1;
        }
    }
    const float sc = 0.044194173824159216f;   // 512^-0.5 folded into q
#pragma unroll
    for (int j = 0; j < 2; ++j) {
        int o = bo + wc * 32 + j * 16 + lr;
        float bqv = bq[o], bkv = bk[o];
#pragma unroll
        for (int i = 0; i < 2; ++i)
#pragma unroll
            for (int r = 0; r < 4; ++r) {
                int m = bm + wr * 32 + i * 16 + 4 * lg + r;
                size_t base = ((size_t)(b * NPOS) + m) * CH + o;
                qT[base] = f2b((aq[i][j][r] + bqv) * sc);
                kT[base] = f2b(ak[i][j][r] + bkv);
            }
    }
#pragma unroll
    for (int i = 0; i < 2; ++i)
#pragma unroll
        for (int r = 0; r < 4; ++r) {
            int o = bo + wc * 32 + i * 16 + 4 * lg + r;
            float bvv = bv[o];
#pragma unroll
            for (int j = 0; j < 2; ++j) {
                int m = bm + wr * 32 + j * 16 + lr;
                vB[((size_t)(b * CH) + o) * NPOS + m] = f2b(av[i][j][r] + bvv);
            }
        }
}

// ---------------------------------------------------------------------------
// K4: flash attention v9. 256 blocks x 8 waves. KVBLK=64, single-buffered
// K+V 64KB tiles, counted vmcnt(8) pipeline, 8-way V chunk swizzle.
// QK mapping (unchanged): wave (mi=w&3, ci=w>>2): S[16 rows][32 keys].
// PV mapping (NEW): wave (pm=w&1 -> 32-row half, pc=w>>1 -> 128-c quarter):
// each V fragment feeds 2 row-subtile MFMAs (V LDS reads halved).
// Branchless online softmax: m_run (QK rows, for P/lsum) and m_pv0/m_pv1
// (PV rows, for acc rescale) track identical sequences from shared mpart.
// ---------------------------------------------------------------------------
__global__ __launch_bounds__(512) __attribute__((amdgpu_waves_per_eu(2, 2)))
void attn_k(
    const ushort* __restrict__ qT, const ushort* __restrict__ kT,
    const ushort* __restrict__ vB, ushort* __restrict__ aoT) {
    __shared__ ushort Ks[KVB * 512];       // 64 KB
    __shared__ ushort Vs[512 * KVB];       // 64 KB
    __shared__ ushort P_lds[64 * 72];      // 9 KB, 144B rows
    __shared__ float mpart[2][4][16];      // [ci][mi][row]

    int id = blockIdx.x;
    int b  = (id & 7) >> 1;
    int mt = ((id >> 3) << 1) | (id & 1);   // 0..63
    int m0 = mt * 64;

    int t = threadIdx.x, l = t & 63, w = t >> 6;   // w 0..7
    int mi = w & 3, ci = w >> 2;                   // QK mapping
    int pm = w & 1, pc = w >> 1;                   // PV mapping
    int lr = l & 15, lg = l >> 4;

    const ushort* kTb = kT + (size_t)b * NPOS * CH;
    const ushort* vBb = vB + (size_t)b * CH * NPOS;

    auto stageK = [&](int n0) {
#pragma unroll
        for (int i = 0; i < 8; ++i) {
            int n = w * 8 + i;
            const ushort* g = kTb + (size_t)(n0 + n) * CH + (l ^ (n & 7)) * 8;
            gld16(&Ks[n * 512], g);
        }
    };
    auto stageV = [&](int n0) {
#pragma unroll
        for (int i = 0; i < 8; ++i) {
            int cb = w * 64 + i * 8;
            int c  = cb + (l >> 3);
            int sc = (l & 7) ^ (c & 7);
            const ushort* g = vBb + (size_t)c * NPOS + n0 + sc * 8;
            gld16(&Vs[cb * KVB], g);
        }
    };

    stageK(0);

    const ushort* qrow = qT + ((size_t)(b * NPOS + m0 + mi * 16 + lr)) * CH + lg * 8;
    bf16x8 qf[16];
#pragma unroll
    for (int ks = 0; ks < 16; ++ks) qf[ks] = *(const bf16x8*)(qrow + ks * 32);

    f32x4 acc0[8], acc1[8];
#pragma unroll
    for (int i = 0; i < 8; ++i) {
        acc0[i] = (f32x4){0.f, 0.f, 0.f, 0.f};
        acc1[i] = (f32x4){0.f, 0.f, 0.f, 0.f};
    }
    float m_run[4], lsum[4], m_pv0[4], m_pv1[4];
#pragma unroll
    for (int r = 0; r < 4; ++r) {
        m_run[r] = -1e30f; lsum[r] = 0.f;
        m_pv0[r] = -1e30f; m_pv1[r] = -1e30f;
    }

    int zk = lr & 7;
    for (int nt = 0; nt < NT; ++nt) {
        int n0 = nt * KVB;
        asm volatile("s_waitcnt vmcnt(0)" ::: "memory");
        __builtin_amdgcn_s_barrier();
        __builtin_amdgcn_sched_barrier(0);
        stageV(n0);
        // ---- QK: S[16 rows (mi)][32 keys (ci half)] (unchanged) ----
        f32x4 s0a = {0.f, 0.f, 0.f, 0.f}, s0b = s0a, s1a = s0a, s1b = s0a;
        const ushort* krow0 = &Ks[(ci * 32 + lr) * 512];
        const ushort* krow1 = &Ks[(ci * 32 + 16 + lr) * 512];
#pragma unroll
        for (int ks = 0; ks < 16; ks += 2) {
            bf16x8 k0a = *(const bf16x8*)(krow0 + (((ks + 0) * 4 + lg) ^ zk) * 8);
            bf16x8 k0b = *(const bf16x8*)(krow0 + (((ks + 1) * 4 + lg) ^ zk) * 8);
            bf16x8 k1a = *(const bf16x8*)(krow1 + (((ks + 0) * 4 + lg) ^ zk) * 8);
            bf16x8 k1b = *(const bf16x8*)(krow1 + (((ks + 1) * 4 + lg) ^ zk) * 8);
            s0a = __builtin_amdgcn_mfma_f32_16x16x32_bf16(qf[ks + 0], k0a, s0a, 0, 0, 0);
            s0b = __builtin_amdgcn_mfma_f32_16x16x32_bf16(qf[ks + 1], k0b, s0b, 0, 0, 0);
            s1a = __builtin_amdgcn_mfma_f32_16x16x32_bf16(qf[ks + 0], k1a, s1a, 0, 0, 0);
            s1b = __builtin_amdgcn_mfma_f32_16x16x32_bf16(qf[ks + 1], k1b, s1b, 0, 0, 0);
        }
        f32x4 s0 = s0a + s0b;
        f32x4 s1 = s1a + s1b;
        float pm_[4];
#pragma unroll
        for (int r = 0; r < 4; ++r) pm_[r] = fmaxf(s0[r], s1[r]);
#pragma unroll
        for (int off = 1; off < 16; off <<= 1)
#pragma unroll
            for (int r = 0; r < 4; ++r) pm_[r] = fmaxf(pm_[r], __shfl_xor(pm_[r], off));
        if (lr == 0) {
#pragma unroll
            for (int r = 0; r < 4; ++r) mpart[ci][mi][4 * lg + r] = pm_[r];
        }
        asm volatile("s_waitcnt lgkmcnt(0)" ::: "memory");
        __builtin_amdgcn_s_barrier();                 // b1: mpart visible
        __builtin_amdgcn_sched_barrier(0);
        if (nt + 1 < NT) stageK((nt + 1) * KVB);
        // ---- branchless softmax, QK rows (for P and lsum) ----
        float aqk[4], p0[4], p1[4];
#pragma unroll
        for (int r = 0; r < 4; ++r) {
            int row = 4 * lg + r;
            float mt2 = fmaxf(mpart[0][mi][row], mpart[1][mi][row]);
            float mnew = fmaxf(m_run[r], mt2);
            aqk[r] = __expf(m_run[r] - mnew);
            m_run[r] = mnew;
        }
#pragma unroll
        for (int r = 0; r < 4; ++r) {
            p0[r] = __expf(s0[r] - m_run[r]);
            p1[r] = __expf(s1[r] - m_run[r]);
            lsum[r] = lsum[r] * aqk[r] + p0[r] + p1[r];
        }
#pragma unroll
        for (int r = 0; r < 4; ++r) {
            int row = mi * 16 + 4 * lg + r;
            P_lds[row * 72 + ci * 32 + lr]      = f2b(p0[r]);
            P_lds[row * 72 + ci * 32 + 16 + lr] = f2b(p1[r]);
        }
        // ---- PV-row alphas (identical recurrence from same mpart) ----
        float apv0[4], apv1[4];
#pragma unroll
        for (int r = 0; r < 4; ++r) {
            int row = 4 * lg + r;
            float ma = fmaxf(mpart[0][pm * 2][row], mpart[1][pm * 2][row]);
            float na = fmaxf(m_pv0[r], ma);
            apv0[r] = __expf(m_pv0[r] - na);
            m_pv0[r] = na;
            float mb = fmaxf(mpart[0][pm * 2 + 1][row], mpart[1][pm * 2 + 1][row]);
            float nb = fmaxf(m_pv1[r], mb);
            apv1[r] = __expf(m_pv1[r] - nb);
            m_pv1[r] = nb;
        }
#pragma unroll
        for (int cs = 0; cs < 8; ++cs) {
            acc0[cs][0] *= apv0[0]; acc0[cs][1] *= apv0[1];
            acc0[cs][2] *= apv0[2]; acc0[cs][3] *= apv0[3];
            acc1[cs][0] *= apv1[0]; acc1[cs][1] *= apv1[1];
            acc1[cs][2] *= apv1[2]; acc1[cs][3] *= apv1[3];
        }
        if (nt + 1 < NT) {
            asm volatile("s_waitcnt vmcnt(8)" ::: "memory");
        } else {
            asm volatile("s_waitcnt vmcnt(0)" ::: "memory");
        }
        asm volatile("s_waitcnt lgkmcnt(0)" ::: "memory");
        __builtin_amdgcn_s_barrier();                 // b2: P visible + V landed
        __builtin_amdgcn_sched_barrier(0);
        // ---- PV: O[32 rows (pm)][128 c (pc)] += P[32][64] . V ----
        int prow0 = (pm * 32 + lr) * 72;
        int prow1 = (pm * 32 + 16 + lr) * 72;
        bf16x8 pa00 = *(const bf16x8*)&P_lds[prow0 + lg * 8];
        bf16x8 pa01 = *(const bf16x8*)&P_lds[prow0 + 32 + lg * 8];
        bf16x8 pa10 = *(const bf16x8*)&P_lds[prow1 + lg * 8];
        bf16x8 pa11 = *(const bf16x8*)&P_lds[prow1 + 32 + lg * 8];
#pragma unroll
        for (int cs = 0; cs < 8; ++cs) {
            int c = pc * 128 + cs * 16 + lr;
            bf16x8 vf0 = *(const bf16x8*)&Vs[c * KVB + (((0 * 4 + lg) ^ (c & 7)) * 8)];
            bf16x8 vf1 = *(const bf16x8*)&Vs[c * KVB + (((1 * 4 + lg) ^ (c & 7)) * 8)];
            acc0[cs] = __builtin_amdgcn_mfma_f32_16x16x32_bf16(pa00, vf0, acc0[cs], 0, 0, 0);
            acc0[cs] = __builtin_amdgcn_mfma_f32_16x16x32_bf16(pa01, vf1, acc0[cs], 0, 0, 0);
            acc1[cs] = __builtin_amdgcn_mfma_f32_16x16x32_bf16(pa10, vf0, acc1[cs], 0, 0, 0);
            acc1[cs] = __builtin_amdgcn_mfma_f32_16x16x32_bf16(pa11, vf1, acc1[cs], 0, 0, 0);
        }
    }
    // ---- final l exchange (QK mapping), then normalize PV rows ----
    float ls[4];
#pragma unroll
    for (int r = 0; r < 4; ++r) ls[r] = lsum[r];
#pragma unroll
    for (int off = 1; off < 16; off <<= 1)
#pragma unroll
        for (int r = 0; r < 4; ++r) ls[r] += __shfl_xor(ls[r], off);
    if (lr == 0) {
#pragma unroll
        for (int r = 0; r < 4; ++r) mpart[ci][mi][4 * lg + r] = ls[r];
    }
    asm volatile("s_waitcnt lgkmcnt(0)" ::: "memory");
    __builtin_amdgcn_s_barrier();
    __builtin_amdgcn_sched_barrier(0);
    float inv0[4], inv1[4];
#pragma unroll
    for (int r = 0; r < 4; ++r) {
        int row = 4 * lg + r;
        inv0[r] = 1.0f / (mpart[0][pm * 2][row] + mpart[1][pm * 2][row]);
        inv1[r] = 1.0f / (mpart[0][pm * 2 + 1][row] + mpart[1][pm * 2 + 1][row]);
    }
#pragma unroll
    for (int cs = 0; cs < 8; ++cs)
#pragma unroll
        for (int r = 0; r < 4; ++r) {
            size_t ro = (size_t)(b * NPOS + m0 + pm * 32 + 4 * lg + r);
            int col = pc * 128 + cs * 16 + lr;
            aoT[ro * CH + col]        = f2b(acc0[cs][r] * inv0[r]);
            aoT[(ro + 16) * CH + col] = f2b(acc1[cs][r] * inv1[r]);
        }
}

// ---------------------------------------------------------------------------
// K5: proj on MFMA + bias + residual, depth-1 load pipeline.
// grid (64 mt, 8 ot, 4 b), 4 waves, wave tile 32o x 32m. No LDS.
// ---------------------------------------------------------------------------
__global__ __launch_bounds__(256) void proj_k(
    const ushort* __restrict__ aoT, const ushort* __restrict__ W4,
    const float* __restrict__ bp, const float* __restrict__ x,
    float* __restrict__ out) {
    int bm = blockIdx.x * 64, bo = blockIdx.y * 64, b = blockIdx.z;
    int t = threadIdx.x, l = t & 63, w = t >> 6;
    int orh = w & 1, mc = w >> 1;
    int lr = l & 15, lg = l >> 4;

    const ushort* wp = W4 + 3 * (size_t)WSZ + (size_t)(bo + orh * 32 + lr) * CH + lg * 8;
    const ushort* ab = aoT + ((size_t)(b * NPOS) + bm + mc * 32 + lr) * CH + lg * 8;

    f32x4 ac[2][2];
#pragma unroll
    for (int i = 0; i < 2; ++i)
#pragma unroll
        for (int j = 0; j < 2; ++j) ac[i][j] = (f32x4){0.f, 0.f, 0.f, 0.f};
    bf16x8 w0 = *(const bf16x8*)(wp);
    bf16x8 w1 = *(const bf16x8*)(wp + 16 * CH);
    bf16x8 b0 = *(const bf16x8*)(ab);
    bf16x8 b1 = *(const bf16x8*)(ab + 16 * CH);
#pragma unroll
    for (int s = 0; s < 16; ++s) {
        bf16x8 nw0, nw1, nb0, nb1;
        if (s < 15) {
            int c1 = (s + 1) * 32;
            nw0 = *(const bf16x8*)(wp + c1);
            nw1 = *(const bf16x8*)(wp + 16 * CH + c1);
            nb0 = *(const bf16x8*)(ab + c1);
            nb1 = *(const bf16x8*)(ab + 16 * CH + c1);
        }
        ac[0][0] = __builtin_amdgcn_mfma_f32_16x16x32_bf16(w0, b0, ac[0][0], 0, 0, 0);
        ac[0][1] = __builtin_amdgcn_mfma_f32_16x16x32_bf16(w0, b1, ac[0][1], 0, 0, 0);
        ac[1][0] = __builtin_amdgcn_mfma_f32_16x16x32_bf16(w1, b0, ac[1][0], 0, 0, 0);
        ac[1][1] = __builtin_amdgcn_mfma_f32_16x16x32_bf16(w1, b1, ac[1][1], 0, 0, 0);
        if (s < 15) { w0 = nw0; w1 = nw1; b0 = nb0; b1 = nb1; }
    }
#pragma unroll
    for (int i = 0; i < 2; ++i)
#pragma unroll
        for (int r = 0; r < 4; ++r) {
            int o = bo + orh * 32 + i * 16 + 4 * lg + r;
            float bpv = bp[o];
#pragma unroll
            for (int j = 0; j < 2; ++j) {
                int m = bm + mc * 32 + j * 16 + lr;
                size_t base = ((size_t)(b * CH) + o) * NPOS + m;
                out[base] = ac[i][j][r] + bpv + x[base];
            }
        }
}

// ---------------------------------------------------------------------------
extern "C" void kernel_launch(void* const* d_in, const int* in_sizes, int n_in,
                              void* d_out, int out_size, void* d_ws, size_t ws_size,
                              hipStream_t stream) {
    const float* x     = (const float*)d_in[0];
    const float* gamma = (const float*)d_in[1];
    const float* beta  = (const float*)d_in[2];
    const float* Wq    = (const float*)d_in[3];
    const float* bq    = (const float*)d_in[4];
    const float* Wk    = (const float*)d_in[5];
    const float* bk    = (const float*)d_in[6];
    const float* Wv    = (const float*)d_in[7];
    const float* bv    = (const float*)d_in[8];
    const float* Wp    = (const float*)d_in[9];
    const float* bp    = (const float*)d_in[10];
    float* out = (float*)d_out;

    const size_t SZ = (size_t)BATCH * CH * NPOS;               // 8,388,608
    const size_t need = (5 * SZ + 4 * WSZ) * 2 + 1024;         // ~86 MB
    if (ws_size < need) return;

    ushort* qT  = (ushort*)d_ws;          // [b][m][o] bf16 (pre-scaled)
    ushort* kT  = qT + SZ;                // [b][m][o] bf16
    ushort* vb  = kT + SZ;                // [b][o][m] bf16
    ushort* hnT = vb + SZ;                // [b][m][c] bf16
    ushort* aoT = hnT + SZ;               // [b][m][c] bf16
    ushort* W4  = aoT + SZ;               // [4][512][512] bf16
    float*  stats = (float*)(W4 + 4 * (size_t)WSZ);

    prep_k<<<640, 256, 0, stream>>>(x, stats, Wq, Wk, Wv, Wp, W4);
    hnT_k<<<dim3(64, 8, 4), 256, 0, stream>>>(x, gamma, beta, stats, hnT);
    qkv3_k<<<dim3(64, 8, 4), 256, 0, stream>>>(hnT, W4, bq, bk, bv, qT, kT, vb);
    attn_k<<<dim3(256), 512, 0, stream>>>(qT, kT, vb, aoT);
    proj_k<<<dim3(64, 8, 4), 256, 0, stream>>>(aoT, W4, bp, x, out);
}

// Round 21
// 424.338 us; speedup vs baseline: 1.1525x; 1.1525x over previous
//
#include <hip/hip_runtime.h>
#include <math.h>

// AttnBlock: GroupNorm -> QKV 1x1 conv -> spatial self-attention -> proj 1x1 conv + residual
// x (4, 512, 64, 64) fp32. B=4, C=512, N=HW=4096, 32 groups of 16 ch.
// Round 21: FINAL — revert to r17/r19 (verified best: 424.6us, 14.1x baseline).
// r20's PV remap hit the 128-VGPR allocator clamp (spill; 245->311us), the
// third register-pressure casualty (r9, r11, r20). attn_k is at the LDS-port
// roofline of this decomposition; non-attn at its L2/launch floor (r17 null).

#define BATCH 4
#define CH    512
#define NPOS  4096
#define NGRP  32
#define GSIZE (16 * NPOS)
#define WSZ   262144   // 512*512
#define KVB   64
#define NT    64       // 4096 / KVB

typedef __attribute__((ext_vector_type(8))) short bf16x8;
typedef __attribute__((ext_vector_type(4))) float f32x4;

__device__ __forceinline__ ushort f2b(float x) {   // fp32 -> bf16 RNE
    uint u = __float_as_uint(x);
    u += 0x7fff + ((u >> 16) & 1);
    return (ushort)(u >> 16);
}

// async global->LDS, 16B per lane (lds base wave-uniform, HW adds lane*16)
__device__ __forceinline__ void gld16(void* lds, const void* g) {
    __builtin_amdgcn_global_load_lds(
        (const __attribute__((address_space(1))) void*)g,
        (__attribute__((address_space(3))) void*)lds, 16, 0, 0);
}

// ---------------------------------------------------------------------------
// K1: merged prep — blocks 0..127: GroupNorm stats (one per (b,g) segment);
// blocks 128..639: W fp32->bf16 conversion. Independent work, one launch.
// ---------------------------------------------------------------------------
__global__ __launch_bounds__(256) void prep_k(
    const float* __restrict__ x, float* __restrict__ stats,
    const float* __restrict__ Wq, const float* __restrict__ Wk,
    const float* __restrict__ Wv, const float* __restrict__ Wp,
    ushort* __restrict__ W4) {
    if (blockIdx.x >= 128) {
        int id = blockIdx.x - 128;           // 512 conversion blocks
        int sel = id >> 7, blk = id & 127;
        const float* src = sel == 0 ? Wq : (sel == 1 ? Wk : (sel == 2 ? Wv : Wp));
        const float4* s4 = (const float4*)(src + (size_t)blk * 2048);
        ushort4* d4 = (ushort4*)(W4 + (size_t)sel * WSZ + (size_t)blk * 2048);
        for (int i = threadIdx.x; i < 512; i += 256) {
            float4 v = s4[i];
            d4[i] = make_ushort4(f2b(v.x), f2b(v.y), f2b(v.z), f2b(v.w));
        }
        return;
    }
    int bg = blockIdx.x;
    const float4* xp = reinterpret_cast<const float4*>(x + (size_t)bg * GSIZE);
    float s1 = 0.f, s2 = 0.f;
    for (int i = threadIdx.x; i < GSIZE / 4; i += 256) {
        float4 v = xp[i];
        s1 += v.x + v.y + v.z + v.w;
        s2 += v.x * v.x + v.y * v.y + v.z * v.z + v.w * v.w;
    }
    for (int off = 32; off > 0; off >>= 1) {
        s1 += __shfl_down(s1, off);
        s2 += __shfl_down(s2, off);
    }
    __shared__ float r1[4], r2[4];
    int wid = threadIdx.x >> 6;
    if ((threadIdx.x & 63) == 0) { r1[wid] = s1; r2[wid] = s2; }
    __syncthreads();
    if (threadIdx.x == 0) {
        float t1 = r1[0] + r1[1] + r1[2] + r1[3];
        float t2 = r2[0] + r2[1] + r2[2] + r2[3];
        float mean = t1 / (float)GSIZE;
        float var  = t2 / (float)GSIZE - mean * mean;
        stats[bg]       = mean;
        stats[128 + bg] = rsqrtf(var + 1e-6f);
    }
}

// ---------------------------------------------------------------------------
// K2: GroupNorm apply + transpose: x[b][c][m] fp32 -> hnT[b][m][c] bf16.
// grid (64 mt, 8 ct, 4 b), 64x64 tiles via LDS.
// ---------------------------------------------------------------------------
__global__ __launch_bounds__(256) void hnT_k(
    const float* __restrict__ x, const float* __restrict__ gamma,
    const float* __restrict__ beta, const float* __restrict__ stats,
    ushort* __restrict__ hnT) {
    int bm = blockIdx.x * 64, c0 = blockIdx.y * 64, b = blockIdx.z;
    __shared__ ushort Ls[64][65];
    int t = threadIdx.x, tx = t & 15, ty = t >> 4;
    const float* xb = x + ((size_t)b * CH + c0) * NPOS + bm;
#pragma unroll
    for (int it = 0; it < 4; ++it) {
        int cc = ty + it * 16;
        int ch = c0 + cc;
        int bg = b * NGRP + (ch >> 4);
        float ga = stats[128 + bg] * gamma[ch];
        float be = beta[ch] - stats[bg] * ga;
        float4 v = *(const float4*)(xb + (size_t)cc * NPOS + tx * 4);
        Ls[cc][tx * 4 + 0] = f2b(v.x * ga + be);
        Ls[cc][tx * 4 + 1] = f2b(v.y * ga + be);
        Ls[cc][tx * 4 + 2] = f2b(v.z * ga + be);
        Ls[cc][tx * 4 + 3] = f2b(v.w * ga + be);
    }
    __syncthreads();
#pragma unroll
    for (int it = 0; it < 4; ++it) {
        int mm = ty + it * 16;
        ushort4 o;
        o.x = Ls[tx * 4 + 0][mm];
        o.y = Ls[tx * 4 + 1][mm];
        o.z = Ls[tx * 4 + 2][mm];
        o.w = Ls[tx * 4 + 3][mm];
        *(ushort4*)(hnT + ((size_t)(b * NPOS) + bm + mm) * CH + c0 + tx * 4) = o;
    }
}

// ---------------------------------------------------------------------------
// K3: QKV GEMM on MFMA, no LDS, depth-1 load pipeline.
// grid (64 mt, 8 ot, 4 b), 4 waves; wave tile 32m x 32o, all 3 outputs.
// Outputs: qT[b][m][o] (pre-scaled), kT[b][m][o], vB[b][o][m].
// ---------------------------------------------------------------------------
__global__ __launch_bounds__(256) void qkv3_k(
    const ushort* __restrict__ hnT, const ushort* __restrict__ W4,
    const float* __restrict__ bq, const float* __restrict__ bk,
    const float* __restrict__ bv,
    ushort* __restrict__ qT, ushort* __restrict__ kT, ushort* __restrict__ vB) {
    int bm = blockIdx.x * 64, bo = blockIdx.y * 64, b = blockIdx.z;
    int t = threadIdx.x, l = t & 63, w = t >> 6;
    int wr = w & 1, wc = w >> 1;
    int lr = l & 15, lg = l >> 4;

    const ushort* ha  = hnT + ((size_t)(b * NPOS) + bm + wr * 32 + lr) * CH + lg * 8;
    const ushort* wqp = W4 + (size_t)(bo + wc * 32 + lr) * CH + lg * 8;
    const ushort* wkp = wqp + WSZ;
    const ushort* wvp = wkp + WSZ;

    f32x4 aq[2][2], ak[2][2], av[2][2];
#pragma unroll
    for (int i = 0; i < 2; ++i)
#pragma unroll
        for (int j = 0; j < 2; ++j) {
            aq[i][j] = (f32x4){0.f, 0.f, 0.f, 0.f};
            ak[i][j] = (f32x4){0.f, 0.f, 0.f, 0.f};
            av[i][j] = (f32x4){0.f, 0.f, 0.f, 0.f};
        }
    // prologue loads (step 0)
    bf16x8 a0 = *(const bf16x8*)(ha);
    bf16x8 a1 = *(const bf16x8*)(ha + 16 * CH);
    bf16x8 q0 = *(const bf16x8*)(wqp);
    bf16x8 q1 = *(const bf16x8*)(wqp + 16 * CH);
    bf16x8 k0 = *(const bf16x8*)(wkp);
    bf16x8 k1 = *(const bf16x8*)(wkp + 16 * CH);
    bf16x8 v0 = *(const bf16x8*)(wvp);
    bf16x8 v1 = *(const bf16x8*)(wvp + 16 * CH);
#pragma unroll
    for (int s = 0; s < 16; ++s) {
        bf16x8 na0, na1, nq0, nq1, nk0, nk1, nv0, nv1;
        if (s < 15) {                          // prefetch step s+1
            int c1 = (s + 1) * 32;
            na0 = *(const bf16x8*)(ha + c1);
            na1 = *(const bf16x8*)(ha + 16 * CH + c1);
            nq0 = *(const bf16x8*)(wqp + c1);
            nq1 = *(const bf16x8*)(wqp + 16 * CH + c1);
            nk0 = *(const bf16x8*)(wkp + c1);
            nk1 = *(const bf16x8*)(wkp + 16 * CH + c1);
            nv0 = *(const bf16x8*)(wvp + c1);
            nv1 = *(const bf16x8*)(wvp + 16 * CH + c1);
        }
        aq[0][0] = __builtin_amdgcn_mfma_f32_16x16x32_bf16(a0, q0, aq[0][0], 0, 0, 0);
        aq[0][1] = __builtin_amdgcn_mfma_f32_16x16x32_bf16(a0, q1, aq[0][1], 0, 0, 0);
        aq[1][0] = __builtin_amdgcn_mfma_f32_16x16x32_bf16(a1, q0, aq[1][0], 0, 0, 0);
        aq[1][1] = __builtin_amdgcn_mfma_f32_16x16x32_bf16(a1, q1, aq[1][1], 0, 0, 0);
        ak[0][0] = __builtin_amdgcn_mfma_f32_16x16x32_bf16(a0, k0, ak[0][0], 0, 0, 0);
        ak[0][1] = __builtin_amdgcn_mfma_f32_16x16x32_bf16(a0, k1, ak[0][1], 0, 0, 0);
        ak[1][0] = __builtin_amdgcn_mfma_f32_16x16x32_bf16(a1, k0, ak[1][0], 0, 0, 0);
        ak[1][1] = __builtin_amdgcn_mfma_f32_16x16x32_bf16(a1, k1, ak[1][1], 0, 0, 0);
        av[0][0] = __builtin_amdgcn_mfma_f32_16x16x32_bf16(v0, a0, av[0][0], 0, 0, 0);
        av[0][1] = __builtin_amdgcn_mfma_f32_16x16x32_bf16(v0, a1, av[0][1], 0, 0, 0);
        av[1][0] = __builtin_amdgcn_mfma_f32_16x16x32_bf16(v1, a0, av[1][0], 0, 0, 0);
        av[1][1] = __builtin_amdgcn_mfma_f32_16x16x32_bf16(v1, a1, av[1][1], 0, 0, 0);
        if (s < 15) {
            a0 = na0; a1 = na1; q0 = nq0; q1 = nq1;
            k0 = nk0; k1 = nk1; v0 = nv0; v1 = nv1;
        }
    }
    const float sc = 0.044194173824159216f;   // 512^-0.5 folded into q
#pragma unroll
    for (int j = 0; j < 2; ++j) {
        int o = bo + wc * 32 + j * 16 + lr;
        float bqv = bq[o], bkv = bk[o];
#pragma unroll
        for (int i = 0; i < 2; ++i)
#pragma unroll
            for (int r = 0; r < 4; ++r) {
                int m = bm + wr * 32 + i * 16 + 4 * lg + r;
                size_t base = ((size_t)(b * NPOS) + m) * CH + o;
                qT[base] = f2b((aq[i][j][r] + bqv) * sc);
                kT[base] = f2b(ak[i][j][r] + bkv);
            }
    }
#pragma unroll
    for (int i = 0; i < 2; ++i)
#pragma unroll
        for (int r = 0; r < 4; ++r) {
            int o = bo + wc * 32 + i * 16 + 4 * lg + r;
            float bvv = bv[o];
#pragma unroll
            for (int j = 0; j < 2; ++j) {
                int m = bm + wr * 32 + j * 16 + lr;
                vB[((size_t)(b * CH) + o) * NPOS + m] = f2b(av[i][j][r] + bvv);
            }
        }
}

// ---------------------------------------------------------------------------
// K4: flash attention v8 (r15/r17/r19 verified, byte-identical). 256 blocks x
// 8 waves. KVBLK=64, single-buffered K+V 64KB tiles, counted vmcnt(8)
// pipeline, 8-way V chunk swizzle, defer-max (T13), deferred-l.
// ---------------------------------------------------------------------------
__global__ __launch_bounds__(512) __attribute__((amdgpu_waves_per_eu(2, 2)))
void attn_k(
    const ushort* __restrict__ qT, const ushort* __restrict__ kT,
    const ushort* __restrict__ vB, ushort* __restrict__ aoT) {
    __shared__ ushort Ks[KVB * 512];       // 64 KB
    __shared__ ushort Vs[512 * KVB];       // 64 KB
    __shared__ ushort P_lds[64 * 72];      // 9 KB, 144B rows
    __shared__ float mpart[2][4][16];      // [ci][mi][row]

    int id = blockIdx.x;
    int b  = (id & 7) >> 1;
    int mt = ((id >> 3) << 1) | (id & 1);   // 0..63
    int m0 = mt * 64;

    int t = threadIdx.x, l = t & 63, w = t >> 6;   // w 0..7
    int mi = w & 3, ci = w >> 2;
    int lr = l & 15, lg = l >> 4;

    const ushort* kTb = kT + (size_t)b * NPOS * CH;
    const ushort* vBb = vB + (size_t)b * CH * NPOS;

    auto stageK = [&](int n0) {
#pragma unroll
        for (int i = 0; i < 8; ++i) {
            int n = w * 8 + i;
            const ushort* g = kTb + (size_t)(n0 + n) * CH + (l ^ (n & 7)) * 8;
            gld16(&Ks[n * 512], g);
        }
    };
    auto stageV = [&](int n0) {
#pragma unroll
        for (int i = 0; i < 8; ++i) {
            int cb = w * 64 + i * 8;
            int c  = cb + (l >> 3);
            int sc = (l & 7) ^ (c & 7);
            const ushort* g = vBb + (size_t)c * NPOS + n0 + sc * 8;
            gld16(&Vs[cb * KVB], g);
        }
    };

    stageK(0);

    const ushort* qrow = qT + ((size_t)(b * NPOS + m0 + mi * 16 + lr)) * CH + lg * 8;
    bf16x8 qf[16];
#pragma unroll
    for (int ks = 0; ks < 16; ++ks) qf[ks] = *(const bf16x8*)(qrow + ks * 32);

    f32x4 acc[16];
#pragma unroll
    for (int i = 0; i < 16; ++i) acc[i] = (f32x4){0.f, 0.f, 0.f, 0.f};
    float m_run[4], lsum[4];
#pragma unroll
    for (int r = 0; r < 4; ++r) { m_run[r] = -1e30f; lsum[r] = 0.f; }

    int zk = lr & 7;
    for (int nt = 0; nt < NT; ++nt) {
        int n0 = nt * KVB;
        asm volatile("s_waitcnt vmcnt(0)" ::: "memory");
        __builtin_amdgcn_s_barrier();
        __builtin_amdgcn_sched_barrier(0);
        stageV(n0);
        f32x4 s0a = {0.f, 0.f, 0.f, 0.f}, s0b = s0a, s1a = s0a, s1b = s0a;
        const ushort* krow0 = &Ks[(ci * 32 + lr) * 512];
        const ushort* krow1 = &Ks[(ci * 32 + 16 + lr) * 512];
#pragma unroll
        for (int ks = 0; ks < 16; ks += 2) {
            bf16x8 k0a = *(const bf16x8*)(krow0 + (((ks + 0) * 4 + lg) ^ zk) * 8);
            bf16x8 k0b = *(const bf16x8*)(krow0 + (((ks + 1) * 4 + lg) ^ zk) * 8);
            bf16x8 k1a = *(const bf16x8*)(krow1 + (((ks + 0) * 4 + lg) ^ zk) * 8);
            bf16x8 k1b = *(const bf16x8*)(krow1 + (((ks + 1) * 4 + lg) ^ zk) * 8);
            s0a = __builtin_amdgcn_mfma_f32_16x16x32_bf16(qf[ks + 0], k0a, s0a, 0, 0, 0);
            s0b = __builtin_amdgcn_mfma_f32_16x16x32_bf16(qf[ks + 1], k0b, s0b, 0, 0, 0);
            s1a = __builtin_amdgcn_mfma_f32_16x16x32_bf16(qf[ks + 0], k1a, s1a, 0, 0, 0);
            s1b = __builtin_amdgcn_mfma_f32_16x16x32_bf16(qf[ks + 1], k1b, s1b, 0, 0, 0);
        }
        f32x4 s0 = s0a + s0b;
        f32x4 s1 = s1a + s1b;
        float pm[4];
#pragma unroll
        for (int r = 0; r < 4; ++r) pm[r] = fmaxf(s0[r], s1[r]);
#pragma unroll
        for (int off = 1; off < 16; off <<= 1)
#pragma unroll
            for (int r = 0; r < 4; ++r) pm[r] = fmaxf(pm[r], __shfl_xor(pm[r], off));
        if (lr == 0) {
#pragma unroll
            for (int r = 0; r < 4; ++r) mpart[ci][mi][4 * lg + r] = pm[r];
        }
        asm volatile("s_waitcnt lgkmcnt(0)" ::: "memory");
        __builtin_amdgcn_s_barrier();
        __builtin_amdgcn_sched_barrier(0);
        if (nt + 1 < NT) stageK((nt + 1) * KVB);
        float mt2[4];
        float growth = -1e30f;
#pragma unroll
        for (int r = 0; r < 4; ++r) {
            int row = 4 * lg + r;
            mt2[r] = fmaxf(mpart[0][mi][row], mpart[1][mi][row]);
            growth = fmaxf(growth, mt2[r] - m_run[r]);
        }
        bool resc = !__all(growth <= 8.0f);
        if (resc) {
            float alpha[4];
#pragma unroll
            for (int r = 0; r < 4; ++r) {
                float mnew = fmaxf(m_run[r], mt2[r]);
                alpha[r] = __expf(m_run[r] - mnew);
                m_run[r] = mnew;
                lsum[r] *= alpha[r];
            }
#pragma unroll
            for (int cs = 0; cs < 16; ++cs) {
                acc[cs][0] *= alpha[0]; acc[cs][1] *= alpha[1];
                acc[cs][2] *= alpha[2]; acc[cs][3] *= alpha[3];
            }
        }
        float p0[4], p1[4];
#pragma unroll
        for (int r = 0; r < 4; ++r) {
            p0[r] = __expf(s0[r] - m_run[r]);
            p1[r] = __expf(s1[r] - m_run[r]);
            lsum[r] += p0[r] + p1[r];
        }
#pragma unroll
        for (int r = 0; r < 4; ++r) {
            int row = mi * 16 + 4 * lg + r;
            P_lds[row * 72 + ci * 32 + lr]      = f2b(p0[r]);
            P_lds[row * 72 + ci * 32 + 16 + lr] = f2b(p1[r]);
        }
        if (nt + 1 < NT) {
            asm volatile("s_waitcnt vmcnt(8)" ::: "memory");
        } else {
            asm volatile("s_waitcnt vmcnt(0)" ::: "memory");
        }
        asm volatile("s_waitcnt lgkmcnt(0)" ::: "memory");
        __builtin_amdgcn_s_barrier();
        __builtin_amdgcn_sched_barrier(0);
        bf16x8 pa0 = *(const bf16x8*)&P_lds[(mi * 16 + lr) * 72 + lg * 8];
        bf16x8 pa1 = *(const bf16x8*)&P_lds[(mi * 16 + lr) * 72 + 32 + lg * 8];
#pragma unroll
        for (int cs = 0; cs < 16; ++cs) {
            int c = ci * 256 + cs * 16 + lr;
            bf16x8 vf0 = *(const bf16x8*)&Vs[c * KVB + (((0 * 4 + lg) ^ (c & 7)) * 8)];
            bf16x8 vf1 = *(const bf16x8*)&Vs[c * KVB + (((1 * 4 + lg) ^ (c & 7)) * 8)];
            acc[cs] = __builtin_amdgcn_mfma_f32_16x16x32_bf16(pa0, vf0, acc[cs], 0, 0, 0);
            acc[cs] = __builtin_amdgcn_mfma_f32_16x16x32_bf16(pa1, vf1, acc[cs], 0, 0, 0);
        }
    }
    float ls[4];
#pragma unroll
    for (int r = 0; r < 4; ++r) ls[r] = lsum[r];
#pragma unroll
    for (int off = 1; off < 16; off <<= 1)
#pragma unroll
        for (int r = 0; r < 4; ++r) ls[r] += __shfl_xor(ls[r], off);
    if (lr == 0) {
#pragma unroll
        for (int r = 0; r < 4; ++r) mpart[ci][mi][4 * lg + r] = ls[r];
    }
    asm volatile("s_waitcnt lgkmcnt(0)" ::: "memory");
    __builtin_amdgcn_s_barrier();
    __builtin_amdgcn_sched_barrier(0);
    float inv[4];
#pragma unroll
    for (int r = 0; r < 4; ++r) {
        int row = 4 * lg + r;
        inv[r] = 1.0f / (mpart[0][mi][row] + mpart[1][mi][row]);
    }
#pragma unroll
    for (int cs = 0; cs < 16; ++cs)
#pragma unroll
        for (int r = 0; r < 4; ++r)
            aoT[((size_t)(b * NPOS + m0 + mi * 16 + 4 * lg + r)) * CH
                + ci * 256 + cs * 16 + lr] = f2b(acc[cs][r] * inv[r]);
}

// ---------------------------------------------------------------------------
// K5: proj on MFMA + bias + residual, depth-1 load pipeline.
// grid (64 mt, 8 ot, 4 b), 4 waves, wave tile 32o x 32m. No LDS.
// ---------------------------------------------------------------------------
__global__ __launch_bounds__(256) void proj_k(
    const ushort* __restrict__ aoT, const ushort* __restrict__ W4,
    const float* __restrict__ bp, const float* __restrict__ x,
    float* __restrict__ out) {
    int bm = blockIdx.x * 64, bo = blockIdx.y * 64, b = blockIdx.z;
    int t = threadIdx.x, l = t & 63, w = t >> 6;
    int orh = w & 1, mc = w >> 1;
    int lr = l & 15, lg = l >> 4;

    const ushort* wp = W4 + 3 * (size_t)WSZ + (size_t)(bo + orh * 32 + lr) * CH + lg * 8;
    const ushort* ab = aoT + ((size_t)(b * NPOS) + bm + mc * 32 + lr) * CH + lg * 8;

    f32x4 ac[2][2];
#pragma unroll
    for (int i = 0; i < 2; ++i)
#pragma unroll
        for (int j = 0; j < 2; ++j) ac[i][j] = (f32x4){0.f, 0.f, 0.f, 0.f};
    bf16x8 w0 = *(const bf16x8*)(wp);
    bf16x8 w1 = *(const bf16x8*)(wp + 16 * CH);
    bf16x8 b0 = *(const bf16x8*)(ab);
    bf16x8 b1 = *(const bf16x8*)(ab + 16 * CH);
#pragma unroll
    for (int s = 0; s < 16; ++s) {
        bf16x8 nw0, nw1, nb0, nb1;
        if (s < 15) {
            int c1 = (s + 1) * 32;
            nw0 = *(const bf16x8*)(wp + c1);
            nw1 = *(const bf16x8*)(wp + 16 * CH + c1);
            nb0 = *(const bf16x8*)(ab + c1);
            nb1 = *(const bf16x8*)(ab + 16 * CH + c1);
        }
        ac[0][0] = __builtin_amdgcn_mfma_f32_16x16x32_bf16(w0, b0, ac[0][0], 0, 0, 0);
        ac[0][1] = __builtin_amdgcn_mfma_f32_16x16x32_bf16(w0, b1, ac[0][1], 0, 0, 0);
        ac[1][0] = __builtin_amdgcn_mfma_f32_16x16x32_bf16(w1, b0, ac[1][0], 0, 0, 0);
        ac[1][1] = __builtin_amdgcn_mfma_f32_16x16x32_bf16(w1, b1, ac[1][1], 0, 0, 0);
        if (s < 15) { w0 = nw0; w1 = nw1; b0 = nb0; b1 = nb1; }
    }
#pragma unroll
    for (int i = 0; i < 2; ++i)
#pragma unroll
        for (int r = 0; r < 4; ++r) {
            int o = bo + orh * 32 + i * 16 + 4 * lg + r;
            float bpv = bp[o];
#pragma unroll
            for (int j = 0; j < 2; ++j) {
                int m = bm + mc * 32 + j * 16 + lr;
                size_t base = ((size_t)(b * CH) + o) * NPOS + m;
                out[base] = ac[i][j][r] + bpv + x[base];
            }
        }
}

// ---------------------------------------------------------------------------
extern "C" void kernel_launch(void* const* d_in, const int* in_sizes, int n_in,
                              void* d_out, int out_size, void* d_ws, size_t ws_size,
                              hipStream_t stream) {
    const float* x     = (const float*)d_in[0];
    const float* gamma = (const float*)d_in[1];
    const float* beta  = (const float*)d_in[2];
    const float* Wq    = (const float*)d_in[3];
    const float* bq    = (const float*)d_in[4];
    const float* Wk    = (const float*)d_in[5];
    const float* bk    = (const float*)d_in[6];
    const float* Wv    = (const float*)d_in[7];
    const float* bv    = (const float*)d_in[8];
    const float* Wp    = (const float*)d_in[9];
    const float* bp    = (const float*)d_in[10];
    float* out = (float*)d_out;

    const size_t SZ = (size_t)BATCH * CH * NPOS;               // 8,388,608
    const size_t need = (5 * SZ + 4 * WSZ) * 2 + 1024;         // ~86 MB
    if (ws_size < need) return;

    ushort* qT  = (ushort*)d_ws;          // [b][m][o] bf16 (pre-scaled)
    ushort* kT  = qT + SZ;                // [b][m][o] bf16
    ushort* vb  = kT + SZ;                // [b][o][m] bf16
    ushort* hnT = vb + SZ;                // [b][m][c] bf16
    ushort* aoT = hnT + SZ;               // [b][m][c] bf16
    ushort* W4  = aoT + SZ;               // [4][512][512] bf16
    float*  stats = (float*)(W4 + 4 * (size_t)WSZ);

    prep_k<<<640, 256, 0, stream>>>(x, stats, Wq, Wk, Wv, Wp, W4);
    hnT_k<<<dim3(64, 8, 4), 256, 0, stream>>>(x, gamma, beta, stats, hnT);
    qkv3_k<<<dim3(64, 8, 4), 256, 0, stream>>>(hnT, W4, bq, bk, bv, qT, kT, vb);
    attn_k<<<dim3(256), 512, 0, stream>>>(qT, kT, vb, aoT);
    proj_k<<<dim3(64, 8, 4), 256, 0, stream>>>(aoT, W4, bp, x, out);
}